// Round 1
// baseline (687.205 us; speedup 1.0000x reference)
//
#include <hip/hip_runtime.h>
#include <math.h>

#define NE 4096
#define NW 8192
#define KK 128
#define GG 1024
#define MM 64
#define JJ 256

// ws layout (floats): 0=recon_ss, 1=w_relu_ss, 2=e_relu_ss, 3=sim_penalty

// ---------------------------------------------------------------------------
// Fused grid-stride reduction over:
//   region 0: sum((actual-prediction)^2)  -> acc[0]   (8,388,608 float4)
//   region 1: sum(relu(W)^2)              -> acc[1]   (  262,144 float4)
//   region 2: sum(relu(E)^2)              -> acc[2]   (  131,072 float4)
// ---------------------------------------------------------------------------
__global__ void k_reduce(const float4* __restrict__ A, const float4* __restrict__ P,
                         const float4* __restrict__ W4, const float4* __restrict__ E4,
                         float* __restrict__ acc) {
    const size_t RQ = (size_t)NE * NW / 4;
    const size_t WQ = (size_t)KK * NW / 4;
    const size_t EQ = (size_t)NE * KK / 4;
    const size_t TOT = RQ + WQ + EQ;

    float r0 = 0.f, r1 = 0.f, r2 = 0.f;
    size_t stride = (size_t)gridDim.x * blockDim.x;
    for (size_t i = (size_t)blockIdx.x * blockDim.x + threadIdx.x; i < TOT; i += stride) {
        if (i < RQ) {
            float4 a = A[i];
            float4 p = P[i];
            float dx = a.x - p.x, dy = a.y - p.y, dz = a.z - p.z, dw = a.w - p.w;
            r0 += dx * dx + dy * dy + dz * dz + dw * dw;
        } else if (i < RQ + WQ) {
            float4 w = W4[i - RQ];
            float x = fmaxf(w.x, 0.f), y = fmaxf(w.y, 0.f);
            float z = fmaxf(w.z, 0.f), u = fmaxf(w.w, 0.f);
            r1 += x * x + y * y + z * z + u * u;
        } else {
            float4 e = E4[i - RQ - WQ];
            float x = fmaxf(e.x, 0.f), y = fmaxf(e.y, 0.f);
            float z = fmaxf(e.z, 0.f), u = fmaxf(e.w, 0.f);
            r2 += x * x + y * y + z * z + u * u;
        }
    }

    // block reduction: wave shuffle, then cross-wave via LDS
    #pragma unroll
    for (int off = 32; off > 0; off >>= 1) {
        r0 += __shfl_down(r0, off);
        r1 += __shfl_down(r1, off);
        r2 += __shfl_down(r2, off);
    }
    __shared__ float lds[3][4];  // up to 4 waves (256 threads)
    int lane = threadIdx.x & 63, wid = threadIdx.x >> 6;
    if (lane == 0) { lds[0][wid] = r0; lds[1][wid] = r1; lds[2][wid] = r2; }
    __syncthreads();
    if (threadIdx.x == 0) {
        int nw = blockDim.x >> 6;
        float s0 = 0.f, s1 = 0.f, s2 = 0.f;
        for (int w = 0; w < nw; ++w) { s0 += lds[0][w]; s1 += lds[1][w]; s2 += lds[2][w]; }
        atomicAdd(acc + 0, s0);
        atomicAdd(acc + 1, s1);
        atomicAdd(acc + 2, s2);
    }
}

// ---------------------------------------------------------------------------
// Sim penalty. Blocks 0..G-1 (128 threads, thread = k):
//   diff_w[g] = sqrt(sum_m sum_k (W[k,sj[g]] - W[k,wi[g,m]])^2)
//   acc[3] += diff_w[g] * sum_m Sw[sj[g], wi[g,m]]
// Block G: entity term:
//   acc[3] += ||E[ri] - E[ej]||_F * sum_j Se[ri, ej[j]]
// ---------------------------------------------------------------------------
__global__ void k_sim(const float* __restrict__ W, const float* __restrict__ E,
                      const float* __restrict__ Sw, const float* __restrict__ Se,
                      const int* __restrict__ row_ind,
                      const int* __restrict__ wi, const int* __restrict__ ej,
                      const int* __restrict__ sj,
                      float* __restrict__ acc) {
    __shared__ int wi_s[MM];
    __shared__ float lds[2][2];
    const int t = threadIdx.x;  // 128 threads
    const int g = blockIdx.x;

    if (g < GG) {
        const int sjv = sj[g];
        if (t < MM) wi_s[t] = wi[g * MM + t];
        __syncthreads();

        const float* Wk = W + (size_t)t * NW;  // t == k
        const float wj = Wk[sjv];
        float a = 0.f;
        #pragma unroll 16
        for (int m = 0; m < MM; ++m) {
            float x = Wk[wi_s[m]] - wj;
            a = fmaf(x, x, a);
        }
        float sw = (t < MM) ? Sw[(size_t)sjv * NW + wi_s[t]] : 0.f;

        #pragma unroll
        for (int off = 32; off > 0; off >>= 1) {
            a += __shfl_down(a, off);
            sw += __shfl_down(sw, off);
        }
        int lane = t & 63, wid = t >> 6;
        if (lane == 0) { lds[0][wid] = a; lds[1][wid] = sw; }
        __syncthreads();
        if (t == 0) {
            float at = lds[0][0] + lds[0][1];
            float swt = lds[1][0] + lds[1][1];
            atomicAdd(acc + 3, sqrtf(at) * swt);
        }
    } else {
        const int ri = row_ind[0];
        float a = 0.f;
        for (int i = t; i < JJ * KK; i += 128) {
            int j = i >> 7, k = i & 127;           // consecutive t -> consecutive k (coalesced)
            float x = E[(size_t)ri * KK + k] - E[(size_t)ej[j] * KK + k];
            a = fmaf(x, x, a);
        }
        float se = 0.f;
        for (int j = t; j < JJ; j += 128) se += Se[(size_t)ri * NE + ej[j]];

        #pragma unroll
        for (int off = 32; off > 0; off >>= 1) {
            a += __shfl_down(a, off);
            se += __shfl_down(se, off);
        }
        int lane = t & 63, wid = t >> 6;
        if (lane == 0) { lds[0][wid] = a; lds[1][wid] = se; }
        __syncthreads();
        if (t == 0) {
            atomicAdd(acc + 3, sqrtf(lds[0][0] + lds[0][1]) * (lds[1][0] + lds[1][1]));
        }
    }
}

__global__ void k_final(const float* __restrict__ acc, const float* __restrict__ lamb,
                        float* __restrict__ out) {
    out[0] = sqrtf(acc[0]) + lamb[0] * (sqrtf(acc[1]) + sqrtf(acc[2])) + acc[3];
}

extern "C" void kernel_launch(void* const* d_in, const int* in_sizes, int n_in,
                              void* d_out, int out_size, void* d_ws, size_t ws_size,
                              hipStream_t stream) {
    const float* actual     = (const float*)d_in[0];
    const float* prediction = (const float*)d_in[1];
    const float* W          = (const float*)d_in[2];
    const float* E          = (const float*)d_in[3];
    const float* Sw         = (const float*)d_in[4];
    const float* Se         = (const float*)d_in[5];
    const float* lamb       = (const float*)d_in[6];
    const int*   row_ind    = (const int*)d_in[7];
    const int*   wi         = (const int*)d_in[8];
    const int*   ej         = (const int*)d_in[9];
    const int*   sj         = (const int*)d_in[10];

    float* acc = (float*)d_ws;
    hipMemsetAsync(acc, 0, 4 * sizeof(float), stream);  // graph-capturable memset node

    k_reduce<<<2048, 256, 0, stream>>>((const float4*)actual, (const float4*)prediction,
                                       (const float4*)W, (const float4*)E, acc);
    k_sim<<<GG + 1, 128, 0, stream>>>(W, E, Sw, Se, row_ind, wi, ej, sj, acc);
    k_final<<<1, 1, 0, stream>>>(acc, lamb, (float*)d_out);
}